// Round 1
// baseline (673.285 us; speedup 1.0000x reference)
//
#include <hip/hip_runtime.h>

typedef __attribute__((ext_vector_type(4))) float f32x4;
typedef __attribute__((ext_vector_type(8))) short short8;
typedef __attribute__((ext_vector_type(2))) unsigned short ushort2v;
typedef __attribute__((ext_vector_type(4))) unsigned short ushort4v;

#define D_MODEL 1024
#define NH 16
#define DK 64
#define BSZ 4
#define SSZ 2048
#define M_TOT (BSZ * SSZ)   // 8192

__device__ __forceinline__ unsigned short f2bf(float f) {
  unsigned int u = __float_as_uint(f);
  u = (u + 0x7FFFu + ((u >> 16) & 1u)) >> 16;   // RTNE
  return (unsigned short)u;
}
__device__ __forceinline__ float bf2f(unsigned short h) {
  return __uint_as_float(((unsigned int)h) << 16);
}

// ---------------------------------------------------------------- convert
__global__ void convert_kernel(const float* __restrict__ x,
                               const float* __restrict__ Qw,
                               const float* __restrict__ Kw,
                               const float* __restrict__ Vw,
                               const float* __restrict__ Ow,
                               unsigned short* __restrict__ xb,
                               unsigned short* __restrict__ wqkv,
                               unsigned short* __restrict__ owb) {
  const int NX = M_TOT * D_MODEL;        // 8388608
  const int NO = D_MODEL * D_MODEL;      // 1048576
  const int NW = 3 * NO;
  int idx = (blockIdx.x * blockDim.x + threadIdx.x) * 4;
  const float* src;
  unsigned short* dst;
  if (idx < NX) {
    src = x + idx; dst = xb + idx;
  } else if (idx < NX + NW) {
    int j = idx - NX;
    dst = wqkv + j;
    if (j < NO)            src = Qw + j;
    else if (j < 2 * NO)   src = Kw + (j - NO);
    else                   src = Vw + (j - 2 * NO);
  } else {
    int j = idx - NX - NW;
    src = Ow + j; dst = owb + j;
  }
  float4 v = *(const float4*)src;
  ushort4v o;
  o.x = f2bf(v.x); o.y = f2bf(v.y); o.z = f2bf(v.z); o.w = f2bf(v.w);
  *(ushort4v*)dst = o;
}

// ---------------------------------------------------------------- GEMM (NT, bf16, 128x128 tile, BK=32)
// MODE 0: N=3072 QKV projection, epilogue scatters to Qb/Kb [BH][S][64] and Vt [BH][64][S] (bf16)
// MODE 1: N=1024 output projection, epilogue writes fp32 row-major
template <int MODE>
__global__ __launch_bounds__(256) void gemm_kernel(const unsigned short* __restrict__ A,
                                                   const unsigned short* __restrict__ Bm,
                                                   unsigned short* __restrict__ oQ,
                                                   unsigned short* __restrict__ oK,
                                                   unsigned short* __restrict__ oV,
                                                   float* __restrict__ oF) {
  __shared__ unsigned short As[128 * 32];
  __shared__ unsigned short Bs[128 * 32];
  const int t = threadIdx.x;
  const int lane = t & 63, wave = t >> 6;
  const int l15 = lane & 15, g = lane >> 4;
  const int wr = wave >> 1, wc = wave & 1;
  const int brow = blockIdx.x * 128;
  const int bcol = blockIdx.y * 128;
  const int rA = t >> 2, c8 = (t & 3) * 8;

  f32x4 acc[4][4] = {};

  for (int k0 = 0; k0 < 1024; k0 += 32) {
    __syncthreads();
#pragma unroll
    for (int i = 0; i < 2; ++i) {
      const unsigned short* sa = A + (size_t)(brow + rA + 64 * i) * 1024 + k0 + c8;
      __builtin_amdgcn_global_load_lds((const __attribute__((address_space(1))) void*)sa,
                                       (__attribute__((address_space(3))) void*)(&As[(t + 256 * i) * 8]),
                                       16, 0, 0);
      const unsigned short* sb = Bm + (size_t)(bcol + rA + 64 * i) * 1024 + k0 + c8;
      __builtin_amdgcn_global_load_lds((const __attribute__((address_space(1))) void*)sb,
                                       (__attribute__((address_space(3))) void*)(&Bs[(t + 256 * i) * 8]),
                                       16, 0, 0);
    }
    __syncthreads();
    short8 a[4], b[4];
#pragma unroll
    for (int m = 0; m < 4; ++m)
      a[m] = *(const short8*)(&As[(wr * 64 + m * 16 + l15) * 32 + g * 8]);
#pragma unroll
    for (int n = 0; n < 4; ++n)
      b[n] = *(const short8*)(&Bs[(wc * 64 + n * 16 + l15) * 32 + g * 8]);
#pragma unroll
    for (int m = 0; m < 4; ++m)
#pragma unroll
      for (int n = 0; n < 4; ++n)
        acc[m][n] = __builtin_amdgcn_mfma_f32_16x16x32_bf16(a[m], b[n], acc[m][n], 0, 0, 0);
  }

  const int mbase = brow + wr * 64;
  const int nbase = bcol + wc * 64;
  if (MODE == 0) {
    const int which = bcol >> 10;   // uniform per block (128 | 1024)
#pragma unroll
    for (int m = 0; m < 4; ++m) {
#pragma unroll
      for (int n = 0; n < 4; ++n) {
#pragma unroll
        for (int r = 0; r < 4; ++r) {
          int mrow = mbase + m * 16 + g * 4 + r;
          int ncol = nbase + n * 16 + l15;
          int b = mrow >> 11, s = mrow & 2047;
          int rem = ncol & 1023;
          int h = rem >> 6, d = rem & 63;
          int bh = b * NH + h;
          unsigned short val = f2bf(acc[m][n][r]);
          if (which == 0)      oQ[((size_t)bh * SSZ + s) * DK + d] = val;
          else if (which == 1) oK[((size_t)bh * SSZ + s) * DK + d] = val;
          else                 oV[((size_t)bh * DK + d) * SSZ + s] = val;
        }
      }
    }
  } else {
#pragma unroll
    for (int m = 0; m < 4; ++m) {
#pragma unroll
      for (int n = 0; n < 4; ++n) {
#pragma unroll
        for (int r = 0; r < 4; ++r) {
          int mrow = mbase + m * 16 + g * 4 + r;
          int ncol = nbase + n * 16 + l15;
          oF[(size_t)mrow * D_MODEL + ncol] = acc[m][n][r];
        }
      }
    }
  }
}

// ---------------------------------------------------------------- RoPE (in-place on bf16 Q/K, folds 0.125 into Q)
__global__ void rope_kernel(unsigned short* __restrict__ Qb,
                            unsigned short* __restrict__ Kb,
                            const int* __restrict__ pos) {
  int idx = blockIdx.x * blockDim.x + threadIdx.x;  // BH*S*32 threads
  int i = idx & 31;
  int s = (idx >> 5) & (SSZ - 1);
  int bh = idx >> 16;
  int b = bh >> 4;
  float p = (float)pos[b * SSZ + s];
  const float KC = 0.28782313662425572f;  // ln(10000)/32
  float invf = expf(-KC * (float)i);
  float ang = p * invf;
  float sn, cs;
  sincosf(ang, &sn, &cs);
  size_t off = ((size_t)bh * SSZ + s) * DK + 2 * i;

  ushort2v q = *(ushort2v*)(Qb + off);
  float qe = bf2f(q.x), qo = bf2f(q.y);
  float re = (qe * cs - qo * sn) * 0.125f;   // fold 1/sqrt(64)
  float ro = (qe * sn + qo * cs) * 0.125f;
  q.x = f2bf(re); q.y = f2bf(ro);
  *(ushort2v*)(Qb + off) = q;

  ushort2v k = *(ushort2v*)(Kb + off);
  float ke = bf2f(k.x), ko = bf2f(k.y);
  float rke = ke * cs - ko * sn;
  float rko = ke * sn + ko * cs;
  k.x = f2bf(rke); k.y = f2bf(rko);
  *(ushort2v*)(Kb + off) = k;
}

// ---------------------------------------------------------------- flash attention (causal)
// grid: (S/64, BH).  4 waves/block, wave owns 16 q rows; KV tiles of 32.
__global__ __launch_bounds__(256) void attn_kernel(const unsigned short* __restrict__ Qb,
                                                   const unsigned short* __restrict__ Kb,
                                                   const unsigned short* __restrict__ Vt,
                                                   unsigned short* __restrict__ Ob) {
  __shared__ unsigned short PL[4 * 16 * 32];
  const int qt = blockIdx.x, bh = blockIdx.y;
  const int lane = threadIdx.x & 63, wave = threadIdx.x >> 6;
  const int l15 = lane & 15, g = lane >> 4;
  const int qw0 = qt * 64 + wave * 16;
  const size_t bhS = (size_t)bh * SSZ;

  short8 qf[2];
#pragma unroll
  for (int ds = 0; ds < 2; ++ds)
    qf[ds] = *(const short8*)(Qb + (bhS + qw0 + l15) * DK + ds * 32 + g * 8);

  f32x4 acc[4] = {};
  float mrun[4], lrun[4];
#pragma unroll
  for (int r = 0; r < 4; ++r) { mrun[r] = -3.0e38f; lrun[r] = 0.f; }

  unsigned short* pl = PL + wave * 512;
  const int njt = (qw0 + 16 + 31) >> 5;

  for (int jt = 0; jt < njt; ++jt) {
    const int j0 = jt * 32;
    f32x4 sc[2] = {};
#pragma unroll
    for (int c = 0; c < 2; ++c) {
#pragma unroll
      for (int ds = 0; ds < 2; ++ds) {
        short8 kf = *(const short8*)(Kb + (bhS + j0 + c * 16 + l15) * DK + ds * 32 + g * 8);
        sc[c] = __builtin_amdgcn_mfma_f32_16x16x32_bf16(qf[ds], kf, sc[c], 0, 0, 0);
      }
    }
    if (j0 + 31 > qw0) {   // only tail tiles need the causal mask
#pragma unroll
      for (int c = 0; c < 2; ++c) {
        int col = j0 + c * 16 + l15;
#pragma unroll
        for (int r = 0; r < 4; ++r) {
          int row = qw0 + g * 4 + r;
          if (col > row) sc[c][r] = -3.0e38f;
        }
      }
    }
    float pr[4];
#pragma unroll
    for (int r = 0; r < 4; ++r) {
      float v = fmaxf(sc[0][r], sc[1][r]);
#pragma unroll
      for (int msk = 1; msk < 16; msk <<= 1) v = fmaxf(v, __shfl_xor(v, msk));
      float mnew = fmaxf(mrun[r], v);
      float corr = __expf(mrun[r] - mnew);
      mrun[r] = mnew;
      float psum = 0.f;
#pragma unroll
      for (int c = 0; c < 2; ++c) {
        float p = __expf(sc[c][r] - mnew);
        sc[c][r] = p;
        psum += p;
      }
#pragma unroll
      for (int msk = 1; msk < 16; msk <<= 1) psum += __shfl_xor(psum, msk);
      lrun[r] = lrun[r] * corr + psum;
      pr[r] = corr;
    }
#pragma unroll
    for (int n = 0; n < 4; ++n)
#pragma unroll
      for (int r = 0; r < 4; ++r)
        acc[n][r] *= pr[r];
    // P (C-layout) -> LDS -> A-layout fragment, private per-wave region, no barrier
#pragma unroll
    for (int c = 0; c < 2; ++c)
#pragma unroll
      for (int r = 0; r < 4; ++r)
        pl[(g * 4 + r) * 32 + c * 16 + l15] = f2bf(sc[c][r]);
    asm volatile("s_waitcnt lgkmcnt(0)" ::: "memory");
    __builtin_amdgcn_sched_barrier(0);
    short8 pf = *(const short8*)(pl + l15 * 32 + g * 8);
#pragma unroll
    for (int n = 0; n < 4; ++n) {
      short8 vf = *(const short8*)(Vt + ((size_t)bh * DK + n * 16 + l15) * SSZ + j0 + g * 8);
      acc[n] = __builtin_amdgcn_mfma_f32_16x16x32_bf16(pf, vf, acc[n], 0, 0, 0);
    }
  }

  const int b = bh >> 4, h = bh & 15;
#pragma unroll
  for (int r = 0; r < 4; ++r) {
    float inv = 1.f / lrun[r];
    int row = qw0 + g * 4 + r;
    size_t base = ((size_t)b * SSZ + row) * D_MODEL + h * DK;
#pragma unroll
    for (int n = 0; n < 4; ++n)
      Ob[base + n * 16 + l15] = f2bf(acc[n][r] * inv);
  }
}

// ---------------------------------------------------------------- launch
extern "C" void kernel_launch(void* const* d_in, const int* in_sizes, int n_in,
                              void* d_out, int out_size, void* d_ws, size_t ws_size,
                              hipStream_t stream) {
  const float* x  = (const float*)d_in[0];
  const int* pos  = (const int*)d_in[1];
  const float* Qw = (const float*)d_in[2];
  const float* Kw = (const float*)d_in[3];
  const float* Vw = (const float*)d_in[4];
  const float* Ow = (const float*)d_in[5];
  float* out = (float*)d_out;

  unsigned short* xb   = (unsigned short*)d_ws;              // 8192*1024
  unsigned short* wqkv = xb + (size_t)M_TOT * D_MODEL;       // 3072*1024
  unsigned short* owb  = wqkv + (size_t)3 * D_MODEL * D_MODEL;
  unsigned short* Qb   = owb + (size_t)D_MODEL * D_MODEL;    // [64][2048][64]
  unsigned short* Kb   = Qb + (size_t)64 * SSZ * DK;
  unsigned short* Vt   = Kb + (size_t)64 * SSZ * DK;         // [64][64][2048]
  unsigned short* Ob   = Vt + (size_t)64 * SSZ * DK;         // [8192][1024]

  // 1. convert inputs to bf16
  {
    int total = M_TOT * D_MODEL + 4 * D_MODEL * D_MODEL;     // 12582912
    convert_kernel<<<total / 4 / 256, 256, 0, stream>>>(x, Qw, Kw, Vw, Ow, xb, wqkv, owb);
  }
  // 2. QKV projection (N=3072)
  gemm_kernel<0><<<dim3(M_TOT / 128, 3072 / 128), 256, 0, stream>>>(xb, wqkv, Qb, Kb, Vt, nullptr);
  // 3. RoPE in place on Q,K
  rope_kernel<<<(64 * SSZ * 32) / 256, 256, 0, stream>>>(Qb, Kb, pos);
  // 4. causal flash attention
  attn_kernel<<<dim3(SSZ / 64, 64), 256, 0, stream>>>(Qb, Kb, Vt, Ob);
  // 5. output projection -> fp32 d_out
  gemm_kernel<1><<<dim3(M_TOT / 128, D_MODEL / 128), 256, 0, stream>>>(Ob, owb, nullptr, nullptr, nullptr, out);
}

// Round 2
// 515.226 us; speedup vs baseline: 1.3068x; 1.3068x over previous
//
#include <hip/hip_runtime.h>

typedef __attribute__((ext_vector_type(4))) float f32x4;
typedef __attribute__((ext_vector_type(8))) short short8;
typedef __attribute__((ext_vector_type(2))) unsigned short ushort2v;
typedef __attribute__((ext_vector_type(4))) unsigned short ushort4v;

#define D_MODEL 1024
#define NH 16
#define DK 64
#define BSZ 4
#define SSZ 2048
#define M_TOT (BSZ * SSZ)   // 8192

__device__ __forceinline__ unsigned short f2bf(float f) {
  unsigned int u = __float_as_uint(f);
  u = (u + 0x7FFFu + ((u >> 16) & 1u)) >> 16;   // RTNE
  return (unsigned short)u;
}
__device__ __forceinline__ float bf2f(unsigned short h) {
  return __uint_as_float(((unsigned int)h) << 16);
}

// ---------------------------------------------------------------- convert
__global__ void convert_kernel(const float* __restrict__ x,
                               const float* __restrict__ Qw,
                               const float* __restrict__ Kw,
                               const float* __restrict__ Vw,
                               const float* __restrict__ Ow,
                               unsigned short* __restrict__ xb,
                               unsigned short* __restrict__ wqkv,
                               unsigned short* __restrict__ owb) {
  const int NX = M_TOT * D_MODEL;        // 8388608
  const int NO = D_MODEL * D_MODEL;      // 1048576
  const int NW = 3 * NO;
  int idx = (blockIdx.x * blockDim.x + threadIdx.x) * 4;
  const float* src;
  unsigned short* dst;
  if (idx < NX) {
    src = x + idx; dst = xb + idx;
  } else if (idx < NX + NW) {
    int j = idx - NX;
    dst = wqkv + j;
    if (j < NO)            src = Qw + j;
    else if (j < 2 * NO)   src = Kw + (j - NO);
    else                   src = Vw + (j - 2 * NO);
  } else {
    int j = idx - NX - NW;
    src = Ow + j; dst = owb + j;
  }
  float4 v = *(const float4*)src;
  ushort4v o;
  o.x = f2bf(v.x); o.y = f2bf(v.y); o.z = f2bf(v.z); o.w = f2bf(v.w);
  *(ushort4v*)dst = o;
}

// ---------------------------------------------------------------- GEMM (NT, bf16, 128x128 tile, BK=32)
template <int MODE>
__global__ __launch_bounds__(256) void gemm_kernel(const unsigned short* __restrict__ A,
                                                   const unsigned short* __restrict__ Bm,
                                                   unsigned short* __restrict__ oQ,
                                                   unsigned short* __restrict__ oK,
                                                   unsigned short* __restrict__ oV,
                                                   float* __restrict__ oF) {
  __shared__ unsigned short As[128 * 32];
  __shared__ unsigned short Bs[128 * 32];
  const int t = threadIdx.x;
  const int lane = t & 63, wave = t >> 6;
  const int l15 = lane & 15, g = lane >> 4;
  const int wr = wave >> 1, wc = wave & 1;
  const int brow = blockIdx.x * 128;
  const int bcol = blockIdx.y * 128;
  const int rA = t >> 2, c8 = (t & 3) * 8;

  f32x4 acc[4][4] = {};

  for (int k0 = 0; k0 < 1024; k0 += 32) {
    __syncthreads();
#pragma unroll
    for (int i = 0; i < 2; ++i) {
      const unsigned short* sa = A + (size_t)(brow + rA + 64 * i) * 1024 + k0 + c8;
      __builtin_amdgcn_global_load_lds((const __attribute__((address_space(1))) void*)sa,
                                       (__attribute__((address_space(3))) void*)(&As[(t + 256 * i) * 8]),
                                       16, 0, 0);
      const unsigned short* sb = Bm + (size_t)(bcol + rA + 64 * i) * 1024 + k0 + c8;
      __builtin_amdgcn_global_load_lds((const __attribute__((address_space(1))) void*)sb,
                                       (__attribute__((address_space(3))) void*)(&Bs[(t + 256 * i) * 8]),
                                       16, 0, 0);
    }
    __syncthreads();
    short8 a[4], b[4];
#pragma unroll
    for (int m = 0; m < 4; ++m)
      a[m] = *(const short8*)(&As[(wr * 64 + m * 16 + l15) * 32 + g * 8]);
#pragma unroll
    for (int n = 0; n < 4; ++n)
      b[n] = *(const short8*)(&Bs[(wc * 64 + n * 16 + l15) * 32 + g * 8]);
#pragma unroll
    for (int m = 0; m < 4; ++m)
#pragma unroll
      for (int n = 0; n < 4; ++n)
        acc[m][n] = __builtin_amdgcn_mfma_f32_16x16x32_bf16(a[m], b[n], acc[m][n], 0, 0, 0);
  }

  const int mbase = brow + wr * 64;
  const int nbase = bcol + wc * 64;
  if (MODE == 0) {
    const int which = bcol >> 10;   // uniform per block (128 | 1024)
#pragma unroll
    for (int m = 0; m < 4; ++m) {
#pragma unroll
      for (int n = 0; n < 4; ++n) {
#pragma unroll
        for (int r = 0; r < 4; ++r) {
          int mrow = mbase + m * 16 + g * 4 + r;
          int ncol = nbase + n * 16 + l15;
          int b = mrow >> 11, s = mrow & 2047;
          int rem = ncol & 1023;
          int h = rem >> 6, d = rem & 63;
          int bh = b * NH + h;
          unsigned short val = f2bf(acc[m][n][r]);
          if (which == 0)      oQ[((size_t)bh * SSZ + s) * DK + d] = val;
          else if (which == 1) oK[((size_t)bh * SSZ + s) * DK + d] = val;
          else                 oV[((size_t)bh * DK + d) * SSZ + s] = val;
        }
      }
    }
  } else {
#pragma unroll
    for (int m = 0; m < 4; ++m) {
#pragma unroll
      for (int n = 0; n < 4; ++n) {
#pragma unroll
        for (int r = 0; r < 4; ++r) {
          int mrow = mbase + m * 16 + g * 4 + r;
          int ncol = nbase + n * 16 + l15;
          oF[(size_t)mrow * D_MODEL + ncol] = acc[m][n][r];
        }
      }
    }
  }
}

// ---------------------------------------------------------------- RoPE (in-place on bf16 Q/K, folds 0.125 into Q)
__global__ void rope_kernel(unsigned short* __restrict__ Qb,
                            unsigned short* __restrict__ Kb,
                            const int* __restrict__ pos) {
  int idx = blockIdx.x * blockDim.x + threadIdx.x;  // BH*S*32 threads
  int i = idx & 31;
  int s = (idx >> 5) & (SSZ - 1);
  int bh = idx >> 16;
  int b = bh >> 4;
  float p = (float)pos[b * SSZ + s];
  const float KC = 0.28782313662425572f;  // ln(10000)/32
  float invf = expf(-KC * (float)i);
  float ang = p * invf;
  float sn, cs;
  sincosf(ang, &sn, &cs);
  size_t off = ((size_t)bh * SSZ + s) * DK + 2 * i;

  ushort2v q = *(ushort2v*)(Qb + off);
  float qe = bf2f(q.x), qo = bf2f(q.y);
  float re = (qe * cs - qo * sn) * 0.125f;   // fold 1/sqrt(64)
  float ro = (qe * sn + qo * cs) * 0.125f;
  q.x = f2bf(re); q.y = f2bf(ro);
  *(ushort2v*)(Qb + off) = q;

  ushort2v k = *(ushort2v*)(Kb + off);
  float ke = bf2f(k.x), ko = bf2f(k.y);
  float rke = ke * cs - ko * sn;
  float rko = ke * sn + ko * cs;
  k.x = f2bf(rke); k.y = f2bf(rko);
  *(ushort2v*)(Kb + off) = k;
}

// ---------------------------------------------------------------- flash attention v2 (causal, swapped QK^T)
// grid: (16, BH). Each block processes q-tiles {bx, 31-bx} (uniform work).
// 4 waves/block, wave owns 16 q rows; KV tiles of 64.
// St = mfma(A=K, B=Q): lane holds one q-row (col=l15), k = c*16 + g*4 + r.
// PV transposed: out^T = mfma(A=Vt, B=Pt): acc rows = d, cols = q.
__global__ __launch_bounds__(256) void attn_kernel(const unsigned short* __restrict__ Qb,
                                                   const unsigned short* __restrict__ Kb,
                                                   const unsigned short* __restrict__ Vt,
                                                   unsigned short* __restrict__ Ob) {
  __shared__ unsigned short PL[4 * 1024];    // per-wave 16q x 64k bf16 (2KB each)
  const int bx = blockIdx.x, bh = blockIdx.y;
  const int lane = threadIdx.x & 63, wave = threadIdx.x >> 6;
  const int l15 = lane & 15, g = lane >> 4;
  const size_t bhS = (size_t)bh * SSZ;
  char* plb = (char*)PL + wave * 2048;
  const int swz = (l15 & 7) << 4;
  const int b = bh >> 4, h = bh & 15;

#pragma unroll 1
  for (int half = 0; half < 2; ++half) {
    const int qt = half ? (31 - bx) : bx;
    const int qw0 = qt * 64 + wave * 16;
    short8 qf[2];
#pragma unroll
    for (int ds = 0; ds < 2; ++ds)
      qf[ds] = *(const short8*)(Qb + (bhS + qw0 + l15) * DK + ds * 32 + g * 8);

    f32x4 acc[4] = {};
    float mrun = -3.0e38f, lrun = 0.f;
    const int njt = qt + 1;

#pragma unroll 1
    for (int jt = 0; jt < njt; ++jt) {
      const int j0 = jt * 64;
      // QK^T swapped: St[k][q]
      f32x4 st[4] = {};
#pragma unroll
      for (int c = 0; c < 4; ++c) {
#pragma unroll
        for (int ds = 0; ds < 2; ++ds) {
          short8 kf = *(const short8*)(Kb + (bhS + j0 + c * 16 + l15) * DK + ds * 32 + g * 8);
          st[c] = __builtin_amdgcn_mfma_f32_16x16x32_bf16(kf, qf[ds], st[c], 0, 0, 0);
        }
      }
      // prefetch V frags (independent of softmax; overlaps latency)
      short8 vf[4][2];
#pragma unroll
      for (int n = 0; n < 4; ++n)
#pragma unroll
        for (int d2 = 0; d2 < 2; ++d2)
          vf[n][d2] = *(const short8*)(Vt + ((size_t)bh * DK + n * 16 + l15) * SSZ + j0 + d2 * 32 + g * 8);

      if (jt == njt - 1) {   // causal mask, only last tile
        const int qrow = qw0 + l15;
#pragma unroll
        for (int c = 0; c < 4; ++c) {
          const int kb = j0 + c * 16 + g * 4;
#pragma unroll
          for (int r = 0; r < 4; ++r)
            if (kb + r > qrow) st[c][r] = -3.0e38f;
        }
      }
      // per-lane softmax over the 16 in-register scores + 2 shuffles (4 groups)
      float mx = st[0][0];
#pragma unroll
      for (int c = 0; c < 4; ++c)
#pragma unroll
        for (int r = 0; r < 4; ++r) mx = fmaxf(mx, st[c][r]);
      mx = fmaxf(mx, __shfl_xor(mx, 16));
      mx = fmaxf(mx, __shfl_xor(mx, 32));
      const float mnew = fmaxf(mrun, mx);
      const float corr = __expf(mrun - mnew);
      mrun = mnew;
      float psum = 0.f;
#pragma unroll
      for (int c = 0; c < 4; ++c)
#pragma unroll
        for (int r = 0; r < 4; ++r) {
          float p = __expf(st[c][r] - mnew);
          st[c][r] = p;
          psum += p;
        }
      psum += __shfl_xor(psum, 16);
      psum += __shfl_xor(psum, 32);
      lrun = lrun * corr + psum;
#pragma unroll
      for (int n = 0; n < 4; ++n)
#pragma unroll
        for (int r = 0; r < 4; ++r) acc[n][r] *= corr;

      // pack P^T -> per-wave LDS (XOR-swizzled rows, bank-balanced)
#pragma unroll
      for (int c = 0; c < 4; ++c) {
        unsigned int w0 = (unsigned)f2bf(st[c][0]) | ((unsigned)f2bf(st[c][1]) << 16);
        unsigned int w1 = (unsigned)f2bf(st[c][2]) | ((unsigned)f2bf(st[c][3]) << 16);
        uint2 ww; ww.x = w0; ww.y = w1;
        *(uint2*)(plb + ((l15 * 128 + c * 32 + g * 8) ^ swz)) = ww;
      }
      asm volatile("s_waitcnt lgkmcnt(0)" ::: "memory");
      __builtin_amdgcn_sched_barrier(0);
      short8 pf[2];
#pragma unroll
      for (int d2 = 0; d2 < 2; ++d2)
        pf[d2] = *(const short8*)(plb + ((l15 * 128 + d2 * 64 + g * 16) ^ swz));
      // PV: out^T[d][q]
#pragma unroll
      for (int n = 0; n < 4; ++n)
#pragma unroll
        for (int d2 = 0; d2 < 2; ++d2)
          acc[n] = __builtin_amdgcn_mfma_f32_16x16x32_bf16(vf[n][d2], pf[d2], acc[n], 0, 0, 0);
    }

    const float inv = 1.f / lrun;
    const size_t base = ((size_t)b * SSZ + qw0 + l15) * D_MODEL + h * DK;
#pragma unroll
    for (int n = 0; n < 4; ++n) {
      unsigned int w0 = (unsigned)f2bf(acc[n][0] * inv) | ((unsigned)f2bf(acc[n][1] * inv) << 16);
      unsigned int w1 = (unsigned)f2bf(acc[n][2] * inv) | ((unsigned)f2bf(acc[n][3] * inv) << 16);
      uint2 ww; ww.x = w0; ww.y = w1;
      *(uint2*)((char*)(Ob + base + n * 16 + g * 4)) = ww;
    }
  }
}

// ---------------------------------------------------------------- launch
extern "C" void kernel_launch(void* const* d_in, const int* in_sizes, int n_in,
                              void* d_out, int out_size, void* d_ws, size_t ws_size,
                              hipStream_t stream) {
  const float* x  = (const float*)d_in[0];
  const int* pos  = (const int*)d_in[1];
  const float* Qw = (const float*)d_in[2];
  const float* Kw = (const float*)d_in[3];
  const float* Vw = (const float*)d_in[4];
  const float* Ow = (const float*)d_in[5];
  float* out = (float*)d_out;

  unsigned short* xb   = (unsigned short*)d_ws;              // 8192*1024
  unsigned short* wqkv = xb + (size_t)M_TOT * D_MODEL;       // 3072*1024
  unsigned short* owb  = wqkv + (size_t)3 * D_MODEL * D_MODEL;
  unsigned short* Qb   = owb + (size_t)D_MODEL * D_MODEL;    // [64][2048][64]
  unsigned short* Kb   = Qb + (size_t)64 * SSZ * DK;
  unsigned short* Vt   = Kb + (size_t)64 * SSZ * DK;         // [64][64][2048]
  unsigned short* Ob   = Vt + (size_t)64 * SSZ * DK;         // [8192][1024]

  // 1. convert inputs to bf16
  {
    int total = M_TOT * D_MODEL + 4 * D_MODEL * D_MODEL;     // 12582912
    convert_kernel<<<total / 4 / 256, 256, 0, stream>>>(x, Qw, Kw, Vw, Ow, xb, wqkv, owb);
  }
  // 2. QKV projection (N=3072)
  gemm_kernel<0><<<dim3(M_TOT / 128, 3072 / 128), 256, 0, stream>>>(xb, wqkv, Qb, Kb, Vt, nullptr);
  // 3. RoPE in place on Q,K
  rope_kernel<<<(64 * SSZ * 32) / 256, 256, 0, stream>>>(Qb, Kb, pos);
  // 4. causal flash attention (paired q-tiles for uniform work)
  attn_kernel<<<dim3(16, 64), 256, 0, stream>>>(Qb, Kb, Vt, Ob);
  // 5. output projection -> fp32 d_out
  gemm_kernel<1><<<dim3(M_TOT / 128, D_MODEL / 128), 256, 0, stream>>>(Ob, owb, nullptr, nullptr, nullptr, out);
}

// Round 5
// 457.006 us; speedup vs baseline: 1.4733x; 1.1274x over previous
//
#include <hip/hip_runtime.h>

typedef __attribute__((ext_vector_type(4))) float f32x4;
typedef __attribute__((ext_vector_type(8))) short short8;
typedef __attribute__((ext_vector_type(2))) unsigned short ushort2v;
typedef __attribute__((ext_vector_type(4))) unsigned short ushort4v;

#define D_MODEL 1024
#define NH 16
#define DK 64
#define BSZ 4
#define SSZ 2048
#define M_TOT (BSZ * SSZ)   // 8192

__device__ __forceinline__ unsigned short f2bf(float f) {
  unsigned int u = __float_as_uint(f);
  u = (u + 0x7FFFu + ((u >> 16) & 1u)) >> 16;   // RTNE
  return (unsigned short)u;
}
__device__ __forceinline__ float bf2f(unsigned short h) {
  return __uint_as_float(((unsigned int)h) << 16);
}

// ---------------------------------------------------------------- convert
__global__ void convert_kernel(const float* __restrict__ x,
                               const float* __restrict__ Qw,
                               const float* __restrict__ Kw,
                               const float* __restrict__ Vw,
                               const float* __restrict__ Ow,
                               unsigned short* __restrict__ xb,
                               unsigned short* __restrict__ wqkv,
                               unsigned short* __restrict__ owb) {
  const int NX = M_TOT * D_MODEL;        // 8388608
  const int NO = D_MODEL * D_MODEL;      // 1048576
  const int NW = 3 * NO;
  int idx = (blockIdx.x * blockDim.x + threadIdx.x) * 4;
  const float* src;
  unsigned short* dst;
  if (idx < NX) {
    src = x + idx; dst = xb + idx;
  } else if (idx < NX + NW) {
    int j = idx - NX;
    dst = wqkv + j;
    if (j < NO)            src = Qw + j;
    else if (j < 2 * NO)   src = Kw + (j - NO);
    else                   src = Vw + (j - 2 * NO);
  } else {
    int j = idx - NX - NW;
    src = Ow + j; dst = owb + j;
  }
  float4 v = *(const float4*)src;
  ushort4v o;
  o.x = f2bf(v.x); o.y = f2bf(v.y); o.z = f2bf(v.z); o.w = f2bf(v.w);
  *(ushort4v*)dst = o;
}

// ---------------------------------------------------------------- GEMM (NT, bf16, 128x128 tile, BK=32)
template <int MODE>
__global__ __launch_bounds__(256) void gemm_kernel(const unsigned short* __restrict__ A,
                                                   const unsigned short* __restrict__ Bm,
                                                   unsigned short* __restrict__ oQ,
                                                   unsigned short* __restrict__ oK,
                                                   unsigned short* __restrict__ oV,
                                                   float* __restrict__ oF) {
  __shared__ unsigned short As[128 * 32];
  __shared__ unsigned short Bs[128 * 32];
  const int t = threadIdx.x;
  const int lane = t & 63, wave = t >> 6;
  const int l15 = lane & 15, g = lane >> 4;
  const int wr = wave >> 1, wc = wave & 1;
  const int brow = blockIdx.x * 128;
  const int bcol = blockIdx.y * 128;
  const int rA = t >> 2, c8 = (t & 3) * 8;

  f32x4 acc[4][4] = {};

  for (int k0 = 0; k0 < 1024; k0 += 32) {
    __syncthreads();
#pragma unroll
    for (int i = 0; i < 2; ++i) {
      const unsigned short* sa = A + (size_t)(brow + rA + 64 * i) * 1024 + k0 + c8;
      __builtin_amdgcn_global_load_lds((const __attribute__((address_space(1))) void*)sa,
                                       (__attribute__((address_space(3))) void*)(&As[(t + 256 * i) * 8]),
                                       16, 0, 0);
      const unsigned short* sb = Bm + (size_t)(bcol + rA + 64 * i) * 1024 + k0 + c8;
      __builtin_amdgcn_global_load_lds((const __attribute__((address_space(1))) void*)sb,
                                       (__attribute__((address_space(3))) void*)(&Bs[(t + 256 * i) * 8]),
                                       16, 0, 0);
    }
    __syncthreads();
    short8 a[4], b[4];
#pragma unroll
    for (int m = 0; m < 4; ++m)
      a[m] = *(const short8*)(&As[(wr * 64 + m * 16 + l15) * 32 + g * 8]);
#pragma unroll
    for (int n = 0; n < 4; ++n)
      b[n] = *(const short8*)(&Bs[(wc * 64 + n * 16 + l15) * 32 + g * 8]);
#pragma unroll
    for (int m = 0; m < 4; ++m)
#pragma unroll
      for (int n = 0; n < 4; ++n)
        acc[m][n] = __builtin_amdgcn_mfma_f32_16x16x32_bf16(a[m], b[n], acc[m][n], 0, 0, 0);
  }

  const int mbase = brow + wr * 64;
  const int nbase = bcol + wc * 64;
  if (MODE == 0) {
    const int which = bcol >> 10;   // uniform per block (128 | 1024)
#pragma unroll
    for (int m = 0; m < 4; ++m) {
#pragma unroll
      for (int n = 0; n < 4; ++n) {
#pragma unroll
        for (int r = 0; r < 4; ++r) {
          int mrow = mbase + m * 16 + g * 4 + r;
          int ncol = nbase + n * 16 + l15;
          int b = mrow >> 11, s = mrow & 2047;
          int rem = ncol & 1023;
          int h = rem >> 6, d = rem & 63;
          int bh = b * NH + h;
          unsigned short val = f2bf(acc[m][n][r]);
          if (which == 0)      oQ[((size_t)bh * SSZ + s) * DK + d] = val;
          else if (which == 1) oK[((size_t)bh * SSZ + s) * DK + d] = val;
          else                 oV[((size_t)bh * DK + d) * SSZ + s] = val;
        }
      }
    }
  } else {
#pragma unroll
    for (int m = 0; m < 4; ++m) {
#pragma unroll
      for (int n = 0; n < 4; ++n) {
#pragma unroll
        for (int r = 0; r < 4; ++r) {
          int mrow = mbase + m * 16 + g * 4 + r;
          int ncol = nbase + n * 16 + l15;
          oF[(size_t)mrow * D_MODEL + ncol] = acc[m][n][r];
        }
      }
    }
  }
}

// ---------------------------------------------------------------- RoPE (in-place on bf16 Q/K, folds 0.125 into Q)
__global__ void rope_kernel(unsigned short* __restrict__ Qb,
                            unsigned short* __restrict__ Kb,
                            const int* __restrict__ pos) {
  int idx = blockIdx.x * blockDim.x + threadIdx.x;  // BH*S*32 threads
  int i = idx & 31;
  int s = (idx >> 5) & (SSZ - 1);
  int bh = idx >> 16;
  int b = bh >> 4;
  float p = (float)pos[b * SSZ + s];
  const float KC = 0.28782313662425572f;  // ln(10000)/32
  float invf = expf(-KC * (float)i);
  float ang = p * invf;
  float sn, cs;
  sincosf(ang, &sn, &cs);
  size_t off = ((size_t)bh * SSZ + s) * DK + 2 * i;

  ushort2v q = *(ushort2v*)(Qb + off);
  float qe = bf2f(q.x), qo = bf2f(q.y);
  float re = (qe * cs - qo * sn) * 0.125f;   // fold 1/sqrt(64)
  float ro = (qe * sn + qo * cs) * 0.125f;
  q.x = f2bf(re); q.y = f2bf(ro);
  *(ushort2v*)(Qb + off) = q;

  ushort2v k = *(ushort2v*)(Kb + off);
  float ke = bf2f(k.x), ko = bf2f(k.y);
  float rke = ke * cs - ko * sn;
  float rko = ke * sn + ko * cs;
  k.x = f2bf(rke); k.y = f2bf(rko);
  *(ushort2v*)(Kb + off) = k;
}

// ---------------------------------------------------------------- flash attention v3 (causal, swapped QK^T, K reg-dbuf)
// grid: (16, BH). Each block processes q-tiles {bx, 31-bx} (uniform work).
// 4 waves/block, wave owns 16 q rows; KV tiles of 64.
// K fragments double-buffered in registers: tile jt+1's loads issue before
// tile jt's compute (issue->use distance ~ full tile, hides L2 latency).
__global__ __launch_bounds__(256) void attn_kernel(const unsigned short* __restrict__ Qb,
                                                   const unsigned short* __restrict__ Kb,
                                                   const unsigned short* __restrict__ Vt,
                                                   unsigned short* __restrict__ Ob) {
  __shared__ unsigned short PL[4 * 1024];    // per-wave 16q x 64k bf16 (2KB each)
  const int bx = blockIdx.x, bh = blockIdx.y;
  const int lane = threadIdx.x & 63, wave = threadIdx.x >> 6;
  const int l15 = lane & 15, g = lane >> 4;
  const size_t bhS = (size_t)bh * SSZ;
  char* plb = (char*)PL + wave * 2048;
  const int swz = (l15 & 7) << 4;
  const int b = bh >> 4, h = bh & 15;

#pragma unroll 1
  for (int half = 0; half < 2; ++half) {
    const int qt = half ? (31 - bx) : bx;
    const int qw0 = qt * 64 + wave * 16;
    short8 qf[2];
#pragma unroll
    for (int ds = 0; ds < 2; ++ds)
      qf[ds] = *(const short8*)(Qb + (bhS + qw0 + l15) * DK + ds * 32 + g * 8);

    f32x4 acc[4] = {};
    float mrun = -3.0e38f, lrun = 0.f;
    const int njt = qt + 1;

    short8 ka[4][2], kb2[4][2];

    auto loadK = [&](short8 (&kf)[4][2], int j0) {
#pragma unroll
      for (int c = 0; c < 4; ++c)
#pragma unroll
        for (int ds = 0; ds < 2; ++ds)
          kf[c][ds] = *(const short8*)(Kb + (bhS + j0 + c * 16 + l15) * DK + ds * 32 + g * 8);
    };

    auto proc = [&](short8 (&kf)[4][2], int j0, bool last) {
      // V loads for THIS tile issue first: QK+softmax (~400cy) covers them
      short8 vf[4][2];
#pragma unroll
      for (int n = 0; n < 4; ++n)
#pragma unroll
        for (int d2 = 0; d2 < 2; ++d2)
          vf[n][d2] = *(const short8*)(Vt + ((size_t)bh * DK + n * 16 + l15) * SSZ + j0 + d2 * 32 + g * 8);

      f32x4 st[4] = {};
#pragma unroll
      for (int c = 0; c < 4; ++c)
#pragma unroll
        for (int ds = 0; ds < 2; ++ds)
          st[c] = __builtin_amdgcn_mfma_f32_16x16x32_bf16(kf[c][ds], qf[ds], st[c], 0, 0, 0);

      if (last) {   // causal mask, only last tile
        const int qrow = qw0 + l15;
#pragma unroll
        for (int c = 0; c < 4; ++c) {
          const int kbse = j0 + c * 16 + g * 4;
#pragma unroll
          for (int r = 0; r < 4; ++r)
            if (kbse + r > qrow) st[c][r] = -3.0e38f;
        }
      }
      // per-lane softmax over the 16 in-register scores + 2 shuffles
      float mx = st[0][0];
#pragma unroll
      for (int c = 0; c < 4; ++c)
#pragma unroll
        for (int r = 0; r < 4; ++r) mx = fmaxf(mx, st[c][r]);
      mx = fmaxf(mx, __shfl_xor(mx, 16));
      mx = fmaxf(mx, __shfl_xor(mx, 32));
      const float mnew = fmaxf(mrun, mx);
      const float corr = __expf(mrun - mnew);
      mrun = mnew;
      float psum = 0.f;
#pragma unroll
      for (int c = 0; c < 4; ++c)
#pragma unroll
        for (int r = 0; r < 4; ++r) {
          float p = __expf(st[c][r] - mnew);
          st[c][r] = p;
          psum += p;
        }
      psum += __shfl_xor(psum, 16);
      psum += __shfl_xor(psum, 32);
      lrun = lrun * corr + psum;
#pragma unroll
      for (int n = 0; n < 4; ++n)
#pragma unroll
        for (int r = 0; r < 4; ++r) acc[n][r] *= corr;

      // pack P^T -> per-wave LDS (XOR-swizzled rows)
#pragma unroll
      for (int c = 0; c < 4; ++c) {
        unsigned int w0 = (unsigned)f2bf(st[c][0]) | ((unsigned)f2bf(st[c][1]) << 16);
        unsigned int w1 = (unsigned)f2bf(st[c][2]) | ((unsigned)f2bf(st[c][3]) << 16);
        uint2 ww; ww.x = w0; ww.y = w1;
        *(uint2*)(plb + ((l15 * 128 + c * 32 + g * 8) ^ swz)) = ww;
      }
      asm volatile("s_waitcnt lgkmcnt(0)" ::: "memory");
      __builtin_amdgcn_sched_barrier(0);
      short8 pf[2];
#pragma unroll
      for (int d2 = 0; d2 < 2; ++d2)
        pf[d2] = *(const short8*)(plb + ((l15 * 128 + d2 * 64 + g * 16) ^ swz));
      // PV: out^T[d][q]
#pragma unroll
      for (int n = 0; n < 4; ++n)
#pragma unroll
        for (int d2 = 0; d2 < 2; ++d2)
          acc[n] = __builtin_amdgcn_mfma_f32_16x16x32_bf16(vf[n][d2], pf[d2], acc[n], 0, 0, 0);
    };

    loadK(ka, 0);
    int jt = 0;
    while (true) {
      if (jt + 1 < njt) loadK(kb2, (jt + 1) * 64);
      proc(ka, jt * 64, jt == njt - 1);
      ++jt; if (jt >= njt) break;
      if (jt + 1 < njt) loadK(ka, (jt + 1) * 64);
      proc(kb2, jt * 64, jt == njt - 1);
      ++jt; if (jt >= njt) break;
    }

    const float inv = 1.f / lrun;
    const size_t base = ((size_t)b * SSZ + qw0 + l15) * D_MODEL + h * DK;
#pragma unroll
    for (int n = 0; n < 4; ++n) {
      unsigned int w0 = (unsigned)f2bf(acc[n][0] * inv) | ((unsigned)f2bf(acc[n][1] * inv) << 16);
      unsigned int w1 = (unsigned)f2bf(acc[n][2] * inv) | ((unsigned)f2bf(acc[n][3] * inv) << 16);
      uint2 ww; ww.x = w0; ww.y = w1;
      *(uint2*)((char*)(Ob + base + n * 16 + g * 4)) = ww;
    }
  }
}

// ---------------------------------------------------------------- launch
extern "C" void kernel_launch(void* const* d_in, const int* in_sizes, int n_in,
                              void* d_out, int out_size, void* d_ws, size_t ws_size,
                              hipStream_t stream) {
  const float* x  = (const float*)d_in[0];
  const int* pos  = (const int*)d_in[1];
  const float* Qw = (const float*)d_in[2];
  const float* Kw = (const float*)d_in[3];
  const float* Vw = (const float*)d_in[4];
  const float* Ow = (const float*)d_in[5];
  float* out = (float*)d_out;

  unsigned short* xb   = (unsigned short*)d_ws;              // 8192*1024
  unsigned short* wqkv = xb + (size_t)M_TOT * D_MODEL;       // 3072*1024
  unsigned short* owb  = wqkv + (size_t)3 * D_MODEL * D_MODEL;
  unsigned short* Qb   = owb + (size_t)D_MODEL * D_MODEL;    // [64][2048][64]
  unsigned short* Kb   = Qb + (size_t)64 * SSZ * DK;
  unsigned short* Vt   = Kb + (size_t)64 * SSZ * DK;         // [64][64][2048]
  unsigned short* Ob   = Vt + (size_t)64 * SSZ * DK;         // [8192][1024]

  // 1. convert inputs to bf16
  {
    int total = M_TOT * D_MODEL + 4 * D_MODEL * D_MODEL;     // 12582912
    convert_kernel<<<total / 4 / 256, 256, 0, stream>>>(x, Qw, Kw, Vw, Ow, xb, wqkv, owb);
  }
  // 2. QKV projection (N=3072)
  gemm_kernel<0><<<dim3(M_TOT / 128, 3072 / 128), 256, 0, stream>>>(xb, wqkv, Qb, Kb, Vt, nullptr);
  // 3. RoPE in place on Q,K
  rope_kernel<<<(64 * SSZ * 32) / 256, 256, 0, stream>>>(Qb, Kb, pos);
  // 4. causal flash attention (paired q-tiles for uniform work)
  attn_kernel<<<dim3(16, 64), 256, 0, stream>>>(Qb, Kb, Vt, Ob);
  // 5. output projection -> fp32 d_out
  gemm_kernel<1><<<dim3(M_TOT / 128, D_MODEL / 128), 256, 0, stream>>>(Ob, owb, nullptr, nullptr, nullptr, out);
}

// Round 6
// 456.286 us; speedup vs baseline: 1.4756x; 1.0016x over previous
//
#include <hip/hip_runtime.h>

typedef __attribute__((ext_vector_type(4))) float f32x4;
typedef __attribute__((ext_vector_type(8))) short short8;
typedef __attribute__((ext_vector_type(2))) unsigned short ushort2v;
typedef __attribute__((ext_vector_type(4))) unsigned short ushort4v;

#define D_MODEL 1024
#define NH 16
#define DK 64
#define BSZ 4
#define SSZ 2048
#define M_TOT (BSZ * SSZ)   // 8192

__device__ __forceinline__ unsigned short f2bf(float f) {
  unsigned int u = __float_as_uint(f);
  u = (u + 0x7FFFu + ((u >> 16) & 1u)) >> 16;   // RTNE
  return (unsigned short)u;
}
__device__ __forceinline__ float bf2f(unsigned short h) {
  return __uint_as_float(((unsigned int)h) << 16);
}
__device__ __forceinline__ unsigned int pk_bf16(float lo, float hi) {
  unsigned int r;
  asm("v_cvt_pk_bf16_f32 %0, %1, %2" : "=v"(r) : "v"(lo), "v"(hi));
  return r;
}

// ---------------------------------------------------------------- convert
__global__ void convert_kernel(const float* __restrict__ x,
                               const float* __restrict__ Qw,
                               const float* __restrict__ Kw,
                               const float* __restrict__ Vw,
                               const float* __restrict__ Ow,
                               unsigned short* __restrict__ xb,
                               unsigned short* __restrict__ wqkv,
                               unsigned short* __restrict__ owb) {
  const int NX = M_TOT * D_MODEL;        // 8388608
  const int NO = D_MODEL * D_MODEL;      // 1048576
  const int NW = 3 * NO;
  int idx = (blockIdx.x * blockDim.x + threadIdx.x) * 4;
  const float* src;
  unsigned short* dst;
  if (idx < NX) {
    src = x + idx; dst = xb + idx;
  } else if (idx < NX + NW) {
    int j = idx - NX;
    dst = wqkv + j;
    if (j < NO)            src = Qw + j;
    else if (j < 2 * NO)   src = Kw + (j - NO);
    else                   src = Vw + (j - 2 * NO);
  } else {
    int j = idx - NX - NW;
    src = Ow + j; dst = owb + j;
  }
  float4 v = *(const float4*)src;
  ushort4v o;
  o.x = f2bf(v.x); o.y = f2bf(v.y); o.z = f2bf(v.z); o.w = f2bf(v.w);
  *(ushort4v*)dst = o;
}

// ---------------------------------------------------------------- GEMM (NT, bf16, 128x128 tile, BK=32)
template <int MODE>
__global__ __launch_bounds__(256) void gemm_kernel(const unsigned short* __restrict__ A,
                                                   const unsigned short* __restrict__ Bm,
                                                   unsigned short* __restrict__ oQ,
                                                   unsigned short* __restrict__ oK,
                                                   unsigned short* __restrict__ oV,
                                                   float* __restrict__ oF) {
  __shared__ unsigned short As[128 * 32];
  __shared__ unsigned short Bs[128 * 32];
  const int t = threadIdx.x;
  const int lane = t & 63, wave = t >> 6;
  const int l15 = lane & 15, g = lane >> 4;
  const int wr = wave >> 1, wc = wave & 1;
  const int brow = blockIdx.x * 128;
  const int bcol = blockIdx.y * 128;
  const int rA = t >> 2, c8 = (t & 3) * 8;

  f32x4 acc[4][4] = {};

  for (int k0 = 0; k0 < 1024; k0 += 32) {
    __syncthreads();
#pragma unroll
    for (int i = 0; i < 2; ++i) {
      const unsigned short* sa = A + (size_t)(brow + rA + 64 * i) * 1024 + k0 + c8;
      __builtin_amdgcn_global_load_lds((const __attribute__((address_space(1))) void*)sa,
                                       (__attribute__((address_space(3))) void*)(&As[(t + 256 * i) * 8]),
                                       16, 0, 0);
      const unsigned short* sb = Bm + (size_t)(bcol + rA + 64 * i) * 1024 + k0 + c8;
      __builtin_amdgcn_global_load_lds((const __attribute__((address_space(1))) void*)sb,
                                       (__attribute__((address_space(3))) void*)(&Bs[(t + 256 * i) * 8]),
                                       16, 0, 0);
    }
    __syncthreads();
    short8 a[4], b[4];
#pragma unroll
    for (int m = 0; m < 4; ++m)
      a[m] = *(const short8*)(&As[(wr * 64 + m * 16 + l15) * 32 + g * 8]);
#pragma unroll
    for (int n = 0; n < 4; ++n)
      b[n] = *(const short8*)(&Bs[(wc * 64 + n * 16 + l15) * 32 + g * 8]);
#pragma unroll
    for (int m = 0; m < 4; ++m)
#pragma unroll
      for (int n = 0; n < 4; ++n)
        acc[m][n] = __builtin_amdgcn_mfma_f32_16x16x32_bf16(a[m], b[n], acc[m][n], 0, 0, 0);
  }

  const int mbase = brow + wr * 64;
  const int nbase = bcol + wc * 64;
  if (MODE == 0) {
    const int which = bcol >> 10;   // uniform per block (128 | 1024)
#pragma unroll
    for (int m = 0; m < 4; ++m) {
#pragma unroll
      for (int n = 0; n < 4; ++n) {
#pragma unroll
        for (int r = 0; r < 4; ++r) {
          int mrow = mbase + m * 16 + g * 4 + r;
          int ncol = nbase + n * 16 + l15;
          int b = mrow >> 11, s = mrow & 2047;
          int rem = ncol & 1023;
          int h = rem >> 6, d = rem & 63;
          int bh = b * NH + h;
          unsigned short val = f2bf(acc[m][n][r]);
          if (which == 0)      oQ[((size_t)bh * SSZ + s) * DK + d] = val;
          else if (which == 1) oK[((size_t)bh * SSZ + s) * DK + d] = val;
          else                 oV[((size_t)bh * DK + d) * SSZ + s] = val;
        }
      }
    }
  } else {
#pragma unroll
    for (int m = 0; m < 4; ++m) {
#pragma unroll
      for (int n = 0; n < 4; ++n) {
#pragma unroll
        for (int r = 0; r < 4; ++r) {
          int mrow = mbase + m * 16 + g * 4 + r;
          int ncol = nbase + n * 16 + l15;
          oF[(size_t)mrow * D_MODEL + ncol] = acc[m][n][r];
        }
      }
    }
  }
}

// ---------------------------------------------------------------- RoPE (in-place on bf16 Q/K, folds 0.125 into Q)
__global__ void rope_kernel(unsigned short* __restrict__ Qb,
                            unsigned short* __restrict__ Kb,
                            const int* __restrict__ pos) {
  int idx = blockIdx.x * blockDim.x + threadIdx.x;  // BH*S*32 threads
  int i = idx & 31;
  int s = (idx >> 5) & (SSZ - 1);
  int bh = idx >> 16;
  int b = bh >> 4;
  float p = (float)pos[b * SSZ + s];
  const float KC = 0.28782313662425572f;  // ln(10000)/32
  float invf = expf(-KC * (float)i);
  float ang = p * invf;
  float sn, cs;
  sincosf(ang, &sn, &cs);
  size_t off = ((size_t)bh * SSZ + s) * DK + 2 * i;

  ushort2v q = *(ushort2v*)(Qb + off);
  float qe = bf2f(q.x), qo = bf2f(q.y);
  float re = (qe * cs - qo * sn) * 0.125f;   // fold 1/sqrt(64)
  float ro = (qe * sn + qo * cs) * 0.125f;
  q.x = f2bf(re); q.y = f2bf(ro);
  *(ushort2v*)(Qb + off) = q;

  ushort2v k = *(ushort2v*)(Kb + off);
  float ke = bf2f(k.x), ko = bf2f(k.y);
  float rke = ke * cs - ko * sn;
  float rko = ke * sn + ko * cs;
  k.x = f2bf(rke); k.y = f2bf(rko);
  *(ushort2v*)(Kb + off) = k;
}

// ---------------------------------------------------------------- flash attention v4
// (causal, swapped QK^T, K reg-dbuf, XCD-swizzled blocks, tree reductions, cvt_pk)
// 1-D grid of 1024 blocks. XCD x = id&7 serves bh in [8x, 8x+8): K/V working
// set 8 x 512KB = 4MB = one XCD's L2 -> K/V loads become L2 hits.
// Each block processes q-tiles {bx, 31-bx} (uniform causal work).
__global__ __launch_bounds__(256) void attn_kernel(const unsigned short* __restrict__ Qb,
                                                   const unsigned short* __restrict__ Kb,
                                                   const unsigned short* __restrict__ Vt,
                                                   unsigned short* __restrict__ Ob) {
  __shared__ unsigned short PL[4 * 1024];    // per-wave 16q x 64k bf16 (2KB each)
  const int id = blockIdx.x;
  const int xcd = id & 7, j = id >> 3;
  const int bh = 8 * xcd + (j & 7);
  const int bx = j >> 3;                     // 0..15
  const int lane = threadIdx.x & 63, wave = threadIdx.x >> 6;
  const int l15 = lane & 15, g = lane >> 4;
  const size_t bhS = (size_t)bh * SSZ;
  char* plb = (char*)PL + wave * 2048;
  const int swz = (l15 & 7) << 4;
  const int b = bh >> 4, h = bh & 15;

#pragma unroll 1
  for (int half = 0; half < 2; ++half) {
    const int qt = half ? (31 - bx) : bx;
    const int qw0 = qt * 64 + wave * 16;
    short8 qf[2];
#pragma unroll
    for (int ds = 0; ds < 2; ++ds)
      qf[ds] = *(const short8*)(Qb + (bhS + qw0 + l15) * DK + ds * 32 + g * 8);

    f32x4 acc[4] = {};
    float mrun = -3.0e38f, lrun = 0.f;
    const int njt = qt + 1;

    short8 ka[4][2], kb2[4][2];

    auto loadK = [&](short8 (&kf)[4][2], int j0) {
#pragma unroll
      for (int c = 0; c < 4; ++c)
#pragma unroll
        for (int ds = 0; ds < 2; ++ds)
          kf[c][ds] = *(const short8*)(Kb + (bhS + j0 + c * 16 + l15) * DK + ds * 32 + g * 8);
    };

    auto proc = [&](short8 (&kf)[4][2], int j0, bool last) {
      // V loads for THIS tile issue first: QK+softmax covers them
      short8 vf[4][2];
#pragma unroll
      for (int n = 0; n < 4; ++n)
#pragma unroll
        for (int d2 = 0; d2 < 2; ++d2)
          vf[n][d2] = *(const short8*)(Vt + ((size_t)bh * DK + n * 16 + l15) * SSZ + j0 + d2 * 32 + g * 8);

      f32x4 st[4] = {};
#pragma unroll
      for (int c = 0; c < 4; ++c)
#pragma unroll
        for (int ds = 0; ds < 2; ++ds)
          st[c] = __builtin_amdgcn_mfma_f32_16x16x32_bf16(kf[c][ds], qf[ds], st[c], 0, 0, 0);

      if (last) {   // causal mask, only last tile
        const int qrow = qw0 + l15;
#pragma unroll
        for (int c = 0; c < 4; ++c) {
          const int kbse = j0 + c * 16 + g * 4;
#pragma unroll
          for (int r = 0; r < 4; ++r)
            if (kbse + r > qrow) st[c][r] = -3.0e38f;
        }
      }
      // tree max (dep depth 4) + 2 shuffles
      float mc[4], sc_[4];
#pragma unroll
      for (int c = 0; c < 4; ++c)
        mc[c] = fmaxf(fmaxf(st[c][0], st[c][1]), fmaxf(st[c][2], st[c][3]));
      float mx = fmaxf(fmaxf(mc[0], mc[1]), fmaxf(mc[2], mc[3]));
      mx = fmaxf(mx, __shfl_xor(mx, 16));
      mx = fmaxf(mx, __shfl_xor(mx, 32));
      const float mnew = fmaxf(mrun, mx);
      const float corr = __expf(mrun - mnew);
      mrun = mnew;
#pragma unroll
      for (int c = 0; c < 4; ++c) {
#pragma unroll
        for (int r = 0; r < 4; ++r)
          st[c][r] = __expf(st[c][r] - mnew);
        sc_[c] = (st[c][0] + st[c][1]) + (st[c][2] + st[c][3]);
      }
      float psum = (sc_[0] + sc_[1]) + (sc_[2] + sc_[3]);
      psum += __shfl_xor(psum, 16);
      psum += __shfl_xor(psum, 32);
      lrun = lrun * corr + psum;
#pragma unroll
      for (int n = 0; n < 4; ++n)
#pragma unroll
        for (int r = 0; r < 4; ++r) acc[n][r] *= corr;

      // pack P^T -> per-wave LDS (XOR-swizzled rows); cvt_pk = 2 ops/4 vals
#pragma unroll
      for (int c = 0; c < 4; ++c) {
        uint2 ww;
        ww.x = pk_bf16(st[c][0], st[c][1]);
        ww.y = pk_bf16(st[c][2], st[c][3]);
        *(uint2*)(plb + ((l15 * 128 + c * 32 + g * 8) ^ swz)) = ww;
      }
      asm volatile("s_waitcnt lgkmcnt(0)" ::: "memory");
      __builtin_amdgcn_sched_barrier(0);
      short8 pf[2];
#pragma unroll
      for (int d2 = 0; d2 < 2; ++d2)
        pf[d2] = *(const short8*)(plb + ((l15 * 128 + d2 * 64 + g * 16) ^ swz));
      // PV: out^T[d][q]
#pragma unroll
      for (int n = 0; n < 4; ++n)
#pragma unroll
        for (int d2 = 0; d2 < 2; ++d2)
          acc[n] = __builtin_amdgcn_mfma_f32_16x16x32_bf16(vf[n][d2], pf[d2], acc[n], 0, 0, 0);
    };

    loadK(ka, 0);
    int jt = 0;
    while (true) {
      if (jt + 1 < njt) loadK(kb2, (jt + 1) * 64);
      proc(ka, jt * 64, jt == njt - 1);
      ++jt; if (jt >= njt) break;
      if (jt + 1 < njt) loadK(ka, (jt + 1) * 64);
      proc(kb2, jt * 64, jt == njt - 1);
      ++jt; if (jt >= njt) break;
    }

    const float inv = 1.f / lrun;
    const size_t base = ((size_t)b * SSZ + qw0 + l15) * D_MODEL + h * DK;
#pragma unroll
    for (int n = 0; n < 4; ++n) {
      uint2 ww;
      ww.x = pk_bf16(acc[n][0] * inv, acc[n][1] * inv);
      ww.y = pk_bf16(acc[n][2] * inv, acc[n][3] * inv);
      *(uint2*)((char*)(Ob + base + n * 16 + g * 4)) = ww;
    }
  }
}

// ---------------------------------------------------------------- launch
extern "C" void kernel_launch(void* const* d_in, const int* in_sizes, int n_in,
                              void* d_out, int out_size, void* d_ws, size_t ws_size,
                              hipStream_t stream) {
  const float* x  = (const float*)d_in[0];
  const int* pos  = (const int*)d_in[1];
  const float* Qw = (const float*)d_in[2];
  const float* Kw = (const float*)d_in[3];
  const float* Vw = (const float*)d_in[4];
  const float* Ow = (const float*)d_in[5];
  float* out = (float*)d_out;

  unsigned short* xb   = (unsigned short*)d_ws;              // 8192*1024
  unsigned short* wqkv = xb + (size_t)M_TOT * D_MODEL;       // 3072*1024
  unsigned short* owb  = wqkv + (size_t)3 * D_MODEL * D_MODEL;
  unsigned short* Qb   = owb + (size_t)D_MODEL * D_MODEL;    // [64][2048][64]
  unsigned short* Kb   = Qb + (size_t)64 * SSZ * DK;
  unsigned short* Vt   = Kb + (size_t)64 * SSZ * DK;         // [64][64][2048]
  unsigned short* Ob   = Vt + (size_t)64 * SSZ * DK;         // [8192][1024]

  // 1. convert inputs to bf16
  {
    int total = M_TOT * D_MODEL + 4 * D_MODEL * D_MODEL;     // 12582912
    convert_kernel<<<total / 4 / 256, 256, 0, stream>>>(x, Qw, Kw, Vw, Ow, xb, wqkv, owb);
  }
  // 2. QKV projection (N=3072)
  gemm_kernel<0><<<dim3(M_TOT / 128, 3072 / 128), 256, 0, stream>>>(xb, wqkv, Qb, Kb, Vt, nullptr);
  // 3. RoPE in place on Q,K
  rope_kernel<<<(64 * SSZ * 32) / 256, 256, 0, stream>>>(Qb, Kb, pos);
  // 4. causal flash attention (XCD-swizzled 1-D grid)
  attn_kernel<<<1024, 256, 0, stream>>>(Qb, Kb, Vt, Ob);
  // 5. output projection -> fp32 d_out
  gemm_kernel<1><<<dim3(M_TOT / 128, D_MODEL / 128), 256, 0, stream>>>(Ob, owb, nullptr, nullptr, nullptr, out);
}